// Round 1
// baseline (218.883 us; speedup 1.0000x reference)
//
#include <hip/hip_runtime.h>
#include <hip/hip_bf16.h>

#define BB  4
#define CC  128
#define ICH 64
#define NN  4096

typedef __attribute__((ext_vector_type(4))) float f32x4;
typedef __attribute__((ext_vector_type(8))) short bf16x8;
typedef unsigned short u16;

static __device__ __forceinline__ f32x4 mfma16(bf16x8 a, bf16x8 b, f32x4 c) {
  return __builtin_amdgcn_mfma_f32_16x16x32_bf16(a, b, c, 0, 0, 0);
}

static __device__ __forceinline__ u16 f2bf(float f) {
  __hip_bfloat16 h = __float2bfloat16(f);
  return *reinterpret_cast<u16*>(&h);
}

// ---------------- Kernel 1: 1x1-conv projections theta/phi/g -> bf16 ----------------
// grid: BB * (NN/32) = 512 blocks, 256 threads
__global__ __launch_bounds__(256) void proj_kernel(
    const float* __restrict__ x,
    const float* __restrict__ gw, const float* __restrict__ gb,
    const float* __restrict__ tw, const float* __restrict__ tb,
    const float* __restrict__ pw, const float* __restrict__ pb,
    u16* __restrict__ th, u16* __restrict__ ph, u16* __restrict__ gg)
{
  __shared__ float xs[CC][32];
  const int b  = blockIdx.x >> 7;
  const int n0 = (blockIdx.x & 127) << 5;
  const int t  = threadIdx.x;

  for (int idx = t; idx < CC * 32; idx += 256) {
    int c = idx >> 5, n = idx & 31;
    xs[c][n] = x[((size_t)(b * CC + c) << 12) + n0 + n];
  }
  __syncthreads();

  const int ic = t & 63;
  const int nb = t >> 6;  // 0..3
  float ag[8], at[8], ap[8];
#pragma unroll
  for (int j = 0; j < 8; ++j) { ag[j] = 0.f; at[j] = 0.f; ap[j] = 0.f; }

  const float4* gw4 = (const float4*)(gw + ic * CC);
  const float4* tw4 = (const float4*)(tw + ic * CC);
  const float4* pw4 = (const float4*)(pw + ic * CC);
  for (int c4 = 0; c4 < CC / 4; ++c4) {
    float4 wg = gw4[c4], wt = tw4[c4], wp = pw4[c4];
#pragma unroll
    for (int cc = 0; cc < 4; ++cc) {
      float wgv = (&wg.x)[cc], wtv = (&wt.x)[cc], wpv = (&wp.x)[cc];
      int c = c4 * 4 + cc;
#pragma unroll
      for (int j = 0; j < 8; ++j) {
        float xv = xs[c][nb + 4 * j];
        ag[j] = fmaf(wgv, xv, ag[j]);
        at[j] = fmaf(wtv, xv, at[j]);
        ap[j] = fmaf(wpv, xv, ap[j]);
      }
    }
  }
  const float bgv = gb[ic], btv = tb[ic], bpv = pb[ic];
#pragma unroll
  for (int j = 0; j < 8; ++j) {
    int n = n0 + nb + 4 * j;
    size_t o = ((size_t)(b * NN + n)) * ICH + ic;
    gg[o] = f2bf(ag[j] + bgv);
    th[o] = f2bf(at[j] + btv);
    ph[o] = f2bf(ap[j] + bpv);
  }
}

// ---------------- Kernel 2: flash attention (f = th.ph^T, softmax, y = P.g) ----------
// grid: BB * (NN/32) = 512 blocks, 128 threads (2 waves, 16 query rows each)
__global__ __launch_bounds__(128) void attn_kernel(
    const u16* __restrict__ thp, const u16* __restrict__ php,
    const u16* __restrict__ ggp, float* __restrict__ y)
{
  __shared__ __align__(16) u16 ph_s[64][72];      // phi tile [m][k]
  __shared__ __align__(16) u16 gt_s[64][80];      // g^T tile [ic][m]
  __shared__ __align__(16) u16 p_s[2][16][72];    // per-wave P tile [n][m]

  const int t    = threadIdx.x;
  const int wave = t >> 6, lane = t & 63;
  const int lhi  = lane >> 4, llo = lane & 15;
  const int b    = blockIdx.x >> 7;
  const int n0   = (blockIdx.x & 127) << 5;
  const int nw   = n0 + wave * 16;
  const size_t bbase = (size_t)b * NN * ICH;

  // Q fragments (A operand), held for the whole kernel
  bf16x8 a_q[2];
#pragma unroll
  for (int kt = 0; kt < 2; ++kt)
    a_q[kt] = *(const bf16x8*)(thp + bbase + (size_t)(nw + llo) * ICH + kt * 32 + lhi * 8);

  const f32x4 fzero = {0.f, 0.f, 0.f, 0.f};
  f32x4 yacc[4];
#pragma unroll
  for (int ci = 0; ci < 4; ++ci) yacc[ci] = fzero;
  float M[4], L[4];
#pragma unroll
  for (int r = 0; r < 4; ++r) { M[r] = -1e30f; L[r] = 0.f; }

  // staging: 512 chunks of 8 bf16; 128 threads -> 4 chunks each
  bf16x8 r_ph[4], r_g[4];
#pragma unroll
  for (int u = 0; u < 4; ++u) {
    int it = t + u * 128;
    int m = it >> 3, e0 = (it & 7) * 8;
    r_ph[u] = *(const bf16x8*)(php + bbase + (size_t)m * ICH + e0);
    r_g[u]  = *(const bf16x8*)(ggp + bbase + (size_t)m * ICH + e0);
  }

  for (int mt = 0; mt < NN / 64; ++mt) {
    __syncthreads();  // previous tile's LDS reads complete
#pragma unroll
    for (int u = 0; u < 4; ++u) {
      int it = t + u * 128;
      int m = it >> 3, e0 = (it & 7) * 8;
      *(bf16x8*)&ph_s[m][e0] = r_ph[u];
#pragma unroll
      for (int j = 0; j < 8; ++j) gt_s[e0 + j][m] = (u16)r_g[u][j];
    }
    if (mt + 1 < NN / 64) {
      int m0n = (mt + 1) * 64;
#pragma unroll
      for (int u = 0; u < 4; ++u) {
        int it = t + u * 128;
        int m = it >> 3, e0 = (it & 7) * 8;
        r_ph[u] = *(const bf16x8*)(php + bbase + (size_t)(m0n + m) * ICH + e0);
        r_g[u]  = *(const bf16x8*)(ggp + bbase + (size_t)(m0n + m) * ICH + e0);
      }
    }
    __syncthreads();  // staged tile visible

    // S = theta . phi^T : per wave 16n x 64m
    f32x4 s[4];
#pragma unroll
    for (int cm = 0; cm < 4; ++cm) {
      f32x4 acc = fzero;
#pragma unroll
      for (int kt = 0; kt < 2; ++kt) {
        bf16x8 bf = *(const bf16x8*)&ph_s[cm * 16 + llo][kt * 32 + lhi * 8];
        acc = mfma16(a_q[kt], bf, acc);
      }
      s[cm] = acc;
    }

    // online softmax (row = lhi*4 + r, cols spread over llo x cm)
    float tmax[4];
#pragma unroll
    for (int r = 0; r < 4; ++r)
      tmax[r] = fmaxf(fmaxf(s[0][r], s[1][r]), fmaxf(s[2][r], s[3][r]));
#pragma unroll
    for (int r = 0; r < 4; ++r) {
#pragma unroll
      for (int d = 1; d < 16; d <<= 1)
        tmax[r] = fmaxf(tmax[r], __shfl_xor(tmax[r], d));
    }
    float corr[4], rsum[4];
#pragma unroll
    for (int r = 0; r < 4; ++r) {
      float mn = fmaxf(M[r], tmax[r]);
      corr[r] = __expf(M[r] - mn);
      M[r] = mn;
      rsum[r] = 0.f;
    }
#pragma unroll
    for (int cm = 0; cm < 4; ++cm) {
#pragma unroll
      for (int r = 0; r < 4; ++r) {
        float p = __expf(s[cm][r] - M[r]);
        rsum[r] += p;
        p_s[wave][lhi * 4 + r][cm * 16 + llo] = f2bf(p);
      }
    }
#pragma unroll
    for (int r = 0; r < 4; ++r) {
#pragma unroll
      for (int d = 1; d < 16; d <<= 1)
        rsum[r] += __shfl_xor(rsum[r], d);
      L[r] = L[r] * corr[r] + rsum[r];
    }
    __syncthreads();  // p_s visible to own wave (compiler/pipe ordering)

    // PV: yacc = yacc*corr + P . g
    bf16x8 pa[2];
#pragma unroll
    for (int kt = 0; kt < 2; ++kt)
      pa[kt] = *(const bf16x8*)&p_s[wave][llo][kt * 32 + lhi * 8];
#pragma unroll
    for (int ci = 0; ci < 4; ++ci) {
#pragma unroll
      for (int r = 0; r < 4; ++r) yacc[ci][r] *= corr[r];
#pragma unroll
      for (int kt = 0; kt < 2; ++kt) {
        bf16x8 bg = *(const bf16x8*)&gt_s[ci * 16 + llo][kt * 32 + lhi * 8];
        yacc[ci] = mfma16(pa[kt], bg, yacc[ci]);
      }
    }
  }

  // epilogue: y = yacc / L
#pragma unroll
  for (int ci = 0; ci < 4; ++ci) {
#pragma unroll
    for (int r = 0; r < 4; ++r) {
      float v = yacc[ci][r] / L[r];
      y[bbase + (size_t)(nw + lhi * 4 + r) * ICH + ci * 16 + llo] = v;
    }
  }
}

// ---------------- Kernel 3: out = W.y + Wb + x (residual) ----------------------------
// grid: BB * (NN/32) = 512 blocks, 256 threads
__global__ __launch_bounds__(256) void out_kernel(
    const float* __restrict__ x, const float* __restrict__ Ww,
    const float* __restrict__ Wb, const float* __restrict__ y,
    float* __restrict__ out)
{
  __shared__ float ys[32][65];
  const int b  = blockIdx.x >> 7;
  const int n0 = (blockIdx.x & 127) << 5;
  const int t  = threadIdx.x;
  for (int idx = t; idx < 32 * 64; idx += 256) {
    int n = idx >> 6, i = idx & 63;
    ys[n][i] = y[((size_t)(b * NN + n0 + n)) * ICH + i];
  }
  __syncthreads();

  const int n = t & 31, c0 = t >> 5;  // c0: 0..7
  float acc[16];
#pragma unroll
  for (int j = 0; j < 16; ++j) acc[j] = 0.f;
  for (int i = 0; i < 64; ++i) {
    float yv = ys[n][i];
#pragma unroll
    for (int j = 0; j < 16; ++j)
      acc[j] = fmaf(Ww[(c0 + 8 * j) * ICH + i], yv, acc[j]);
  }
#pragma unroll
  for (int j = 0; j < 16; ++j) {
    int c = c0 + 8 * j;
    size_t o = ((size_t)(b * CC + c) << 12) + n0 + n;
    out[o] = acc[j] + Wb[c] + x[o];
  }
}

extern "C" void kernel_launch(void* const* d_in, const int* in_sizes, int n_in,
                              void* d_out, int out_size, void* d_ws, size_t ws_size,
                              hipStream_t stream) {
  const float* x  = (const float*)d_in[0];
  const float* gw = (const float*)d_in[1];
  const float* gb = (const float*)d_in[2];
  const float* tw = (const float*)d_in[3];
  const float* tb = (const float*)d_in[4];
  const float* pw = (const float*)d_in[5];
  const float* pb = (const float*)d_in[6];
  const float* Ww = (const float*)d_in[7];
  const float* Wb = (const float*)d_in[8];
  float* out = (float*)d_out;

  char* ws = (char*)d_ws;
  const size_t seg = (size_t)BB * NN * ICH;  // elements per projection array
  u16*   th = (u16*)(ws);
  u16*   ph = (u16*)(ws + seg * 2);
  u16*   gg = (u16*)(ws + seg * 4);
  float* y  = (float*)(ws + seg * 6);

  proj_kernel<<<512, 256, 0, stream>>>(x, gw, gb, tw, tb, pw, pb, th, ph, gg);
  attn_kernel<<<512, 128, 0, stream>>>(th, ph, gg, y);
  out_kernel<<<512, 256, 0, stream>>>(x, Ww, Wb, y, out);
}

// Round 2
// 133.483 us; speedup vs baseline: 1.6398x; 1.6398x over previous
//
#include <hip/hip_runtime.h>
#include <hip/hip_bf16.h>

#define BB  4
#define CC  128
#define ICH 64
#define NN  4096
#define SS  4          // KV split factor

typedef __attribute__((ext_vector_type(4))) float f32x4;
typedef __attribute__((ext_vector_type(8))) short bf16x8;
typedef unsigned short u16;

static __device__ __forceinline__ f32x4 mfma16(bf16x8 a, bf16x8 b, f32x4 c) {
  return __builtin_amdgcn_mfma_f32_16x16x32_bf16(a, b, c, 0, 0, 0);
}
static __device__ __forceinline__ u16 f2bf(float f) {
  __hip_bfloat16 h = __float2bfloat16(f);
  return *reinterpret_cast<u16*>(&h);
}
static __device__ __forceinline__ float bf2f(u16 u) {
  union { unsigned int i; float f; } v; v.i = ((unsigned int)u) << 16; return v.f;
}
static __device__ __forceinline__ void gl_lds16(const void* g, void* l) {
  __builtin_amdgcn_global_load_lds((const __attribute__((address_space(1))) void*)g,
                                   (__attribute__((address_space(3))) void*)l, 16, 0, 0);
}

// ---------------- Kernel 1: projections theta/phi (-> [b][n][ic]) and g -> [b][ic][n]
// grid: BB * (NN/32) = 512 blocks, 256 threads
__global__ __launch_bounds__(256) void proj_kernel(
    const float* __restrict__ x,
    const float* __restrict__ gw, const float* __restrict__ gb,
    const float* __restrict__ tw, const float* __restrict__ tb,
    const float* __restrict__ pw, const float* __restrict__ pb,
    u16* __restrict__ th, u16* __restrict__ ph, u16* __restrict__ gt)
{
  __shared__ float xs[CC][32];
  __shared__ u16 gs[64][34];   // padded: 17-dword stride -> conflict-free column writes
  const int b  = blockIdx.x >> 7;
  const int n0 = (blockIdx.x & 127) << 5;
  const int t  = threadIdx.x;

  for (int idx = t; idx < CC * 32; idx += 256) {
    int c = idx >> 5, n = idx & 31;
    xs[c][n] = x[((size_t)(b * CC + c) << 12) + n0 + n];
  }
  __syncthreads();

  const int ic = t & 63;
  const int nb = t >> 6;  // 0..3
  float ag[8], at[8], ap[8];
#pragma unroll
  for (int j = 0; j < 8; ++j) { ag[j] = 0.f; at[j] = 0.f; ap[j] = 0.f; }

  const float4* gw4 = (const float4*)(gw + ic * CC);
  const float4* tw4 = (const float4*)(tw + ic * CC);
  const float4* pw4 = (const float4*)(pw + ic * CC);
  for (int c4 = 0; c4 < CC / 4; ++c4) {
    float4 wg = gw4[c4], wt = tw4[c4], wp = pw4[c4];
#pragma unroll
    for (int cc = 0; cc < 4; ++cc) {
      float wgv = (&wg.x)[cc], wtv = (&wt.x)[cc], wpv = (&wp.x)[cc];
      int c = c4 * 4 + cc;
#pragma unroll
      for (int j = 0; j < 8; ++j) {
        float xv = xs[c][nb + 4 * j];
        ag[j] = fmaf(wgv, xv, ag[j]);
        at[j] = fmaf(wtv, xv, at[j]);
        ap[j] = fmaf(wpv, xv, ap[j]);
      }
    }
  }
  const float bgv = gb[ic], btv = tb[ic], bpv = pb[ic];
#pragma unroll
  for (int j = 0; j < 8; ++j) {
    int n = n0 + nb + 4 * j;
    size_t o = ((size_t)(b * NN + n)) * ICH + ic;
    th[o] = f2bf(at[j] + btv);
    ph[o] = f2bf(ap[j] + bpv);
    gs[ic][nb + 4 * j] = f2bf(ag[j] + bgv);
  }
  __syncthreads();
  // write g^T tile [64 ic][32 n] coalesced-ish (16B per thread)
  {
    const int row = t >> 2, ch = t & 3;
    u16 tmp[8];
#pragma unroll
    for (int j = 0; j < 8; ++j) tmp[j] = gs[row][ch * 8 + j];
    size_t go = ((size_t)(b * ICH + row)) * NN + n0 + ch * 8;
    *(bf16x8*)(gt + go) = *(bf16x8*)tmp;
  }
}

// ---------------- Kernel 2: flash attention with 4-way KV split --------------------
// grid: BB * (NN/32) * SS = 2048 blocks, 128 threads (2 waves, 16 query rows each)
__global__ __launch_bounds__(128, 4) void attn_kernel(
    const u16* __restrict__ thp, const u16* __restrict__ php,
    const u16* __restrict__ gtp, u16* __restrict__ yp, float2* __restrict__ ml)
{
  // all tiles XOR-swizzled: lds[row*128 + (e ^ ((row&7)<<4))] holds element byte e of row
  __shared__ __align__(16) u16 ph_s[4096];      // phi tile   [64 m][64 ic]   8KB
  __shared__ __align__(16) u16 gt_s[4096];      // g^T tile   [64 ic][64 m]   8KB
  __shared__ __align__(16) u16 p_s[2][1024];    // P tile/wave [16 n][64 m]   2KB each

  const int t    = threadIdx.x;
  const int wave = t >> 6, lane = t & 63;
  const int lhi  = lane >> 4, llo = lane & 15;
  const int bid  = blockIdx.x;
  const int s    = bid & 3;
  const int rb   = (bid >> 2) & 127;
  const int b    = bid >> 9;
  const int n0   = rb << 5;
  const int nw   = n0 + wave * 16;
  const size_t bbase = (size_t)b * NN * ICH;

  // inverse-swizzle chunk offset for staging (lane-constant)
  const int koff = 16 * ((lane & 7) ^ (lane >> 3));
  const int swz  = (llo & 7) << 4;
  const int e0k0 = (lhi * 16) ^ swz;          // kt=0 element-byte offset
  const int e0k1 = (64 + lhi * 16) ^ swz;     // kt=1

  // Q fragments
  bf16x8 a_q[2];
#pragma unroll
  for (int kt = 0; kt < 2; ++kt)
    a_q[kt] = *(const bf16x8*)(thp + bbase + (size_t)(nw + llo) * ICH + kt * 32 + lhi * 8);

  const f32x4 fzero = {0.f, 0.f, 0.f, 0.f};
  f32x4 yacc[4];
#pragma unroll
  for (int ci = 0; ci < 4; ++ci) yacc[ci] = fzero;
  float M[4], L[4];
#pragma unroll
  for (int r = 0; r < 4; ++r) { M[r] = -1e30f; L[r] = 0.f; }

  // per-lane global byte offsets for staging (chunk k = u*2+wave covers rows k*8 + lane>>3)
  const char* ph_g = (const char*)php + bbase * 2;
  const char* gt_g = (const char*)gtp + (size_t)b * ICH * NN * 2;

  const int m_start = s * (NN / SS);
  for (int mt = 0; mt < (NN / SS) / 64; ++mt) {
    const int m0 = m_start + mt * 64;
    // stage: 8 x global_load_lds_dwordx4 per thread (4 ph + 4 gt)
#pragma unroll
    for (int u = 0; u < 4; ++u) {
      const int k = u * 2 + wave;
      const int row = k * 8 + (lane >> 3);
      gl_lds16(ph_g + (size_t)(m0 + row) * 128 + koff, (char*)ph_s + k * 1024);
      gl_lds16(gt_g + (size_t)row * (NN * 2) + m0 * 2 + koff, (char*)gt_s + k * 1024);
    }
    __syncthreads();   // drains vmcnt -> staged tiles visible

    // S = theta . phi^T
    f32x4 sacc[4];
#pragma unroll
    for (int cm = 0; cm < 4; ++cm) {
      const char* base = (const char*)ph_s + cm * 2048 + llo * 128;
      f32x4 acc = fzero;
      acc = mfma16(a_q[0], *(const bf16x8*)(base + e0k0), acc);
      acc = mfma16(a_q[1], *(const bf16x8*)(base + e0k1), acc);
      sacc[cm] = acc;
    }

    // online softmax (row = lhi*4 + r, cols spread over llo x cm)
    float tmax[4];
#pragma unroll
    for (int r = 0; r < 4; ++r)
      tmax[r] = fmaxf(fmaxf(sacc[0][r], sacc[1][r]), fmaxf(sacc[2][r], sacc[3][r]));
#pragma unroll
    for (int r = 0; r < 4; ++r) {
#pragma unroll
      for (int d = 1; d < 16; d <<= 1)
        tmax[r] = fmaxf(tmax[r], __shfl_xor(tmax[r], d));
    }
    float corr[4], rsum[4];
#pragma unroll
    for (int r = 0; r < 4; ++r) {
      float mn = fmaxf(M[r], tmax[r]);
      corr[r] = __expf(M[r] - mn);
      M[r] = mn;
      rsum[r] = 0.f;
    }
    char* pw = (char*)p_s[wave];
#pragma unroll
    for (int cm = 0; cm < 4; ++cm) {
#pragma unroll
      for (int r = 0; r < 4; ++r) {
        float p = __expf(sacc[cm][r] - M[r]);
        rsum[r] += p;
        const int row = lhi * 4 + r;
        *(u16*)(pw + row * 128 + ((cm * 32 + llo * 2) ^ ((row & 7) << 4))) = f2bf(p);
      }
    }
#pragma unroll
    for (int r = 0; r < 4; ++r) {
#pragma unroll
      for (int d = 1; d < 16; d <<= 1)
        rsum[r] += __shfl_xor(rsum[r], d);
      L[r] = L[r] * corr[r] + rsum[r];
    }

    // PV: yacc = yacc*corr + P . g   (p_s is wave-private; compiler orders ds ops)
    const char* pb_ = (const char*)p_s[wave] + llo * 128;
    bf16x8 pa0 = *(const bf16x8*)(pb_ + e0k0);
    bf16x8 pa1 = *(const bf16x8*)(pb_ + e0k1);
#pragma unroll
    for (int ci = 0; ci < 4; ++ci) {
#pragma unroll
      for (int r = 0; r < 4; ++r) yacc[ci][r] *= corr[r];
      const char* gbase = (const char*)gt_s + ci * 2048 + llo * 128;
      yacc[ci] = mfma16(pa0, *(const bf16x8*)(gbase + e0k0), yacc[ci]);
      yacc[ci] = mfma16(pa1, *(const bf16x8*)(gbase + e0k1), yacc[ci]);
    }
    __syncthreads();   // all LDS reads done before next tile's staging
  }

  // epilogue: partial numerator (bf16) + (M, L)
  const size_t pbase = ((size_t)s * BB + b) * NN;
#pragma unroll
  for (int ci = 0; ci < 4; ++ci) {
#pragma unroll
    for (int r = 0; r < 4; ++r)
      yp[(pbase + nw + lhi * 4 + r) * ICH + ci * 16 + llo] = f2bf(yacc[ci][r]);
  }
  if (llo == 0) {
#pragma unroll
    for (int r = 0; r < 4; ++r)
      ml[pbase + nw + lhi * 4 + r] = make_float2(M[r], L[r]);
  }
}

// ---------------- Kernel 3: combine partials, out = W.y + Wb + x ---------------------
// grid: BB * (NN/32) = 512 blocks, 256 threads
__global__ __launch_bounds__(256) void out_kernel(
    const float* __restrict__ x, const float* __restrict__ Ww,
    const float* __restrict__ Wb, const u16* __restrict__ yp,
    const float2* __restrict__ ml, float* __restrict__ out)
{
  __shared__ float ys[32][65];
  __shared__ float2 mls[SS][32];
  const int b  = blockIdx.x >> 7;
  const int n0 = (blockIdx.x & 127) << 5;
  const int t  = threadIdx.x;

  if (t < SS * 32) {
    int s = t >> 5, n = t & 31;
    mls[s][n] = ml[((size_t)s * BB + b) * NN + n0 + n];
  }
  __syncthreads();

  const size_t sstr = (size_t)BB * NN * ICH;
  for (int idx = t; idx < 32 * 64; idx += 256) {
    int n = idx >> 6, i = idx & 63;
    float2 a0 = mls[0][n], a1 = mls[1][n], a2 = mls[2][n], a3 = mls[3][n];
    float Mx = fmaxf(fmaxf(a0.x, a1.x), fmaxf(a2.x, a3.x));
    float w0 = __expf(a0.x - Mx), w1 = __expf(a1.x - Mx);
    float w2 = __expf(a2.x - Mx), w3 = __expf(a3.x - Mx);
    size_t base = ((size_t)(b * NN + n0 + n)) * ICH + i;
    float num = w0 * bf2f(yp[base]) + w1 * bf2f(yp[base + sstr]) +
                w2 * bf2f(yp[base + 2 * sstr]) + w3 * bf2f(yp[base + 3 * sstr]);
    float den = w0 * a0.y + w1 * a1.y + w2 * a2.y + w3 * a3.y;
    ys[n][i] = num / den;
  }
  __syncthreads();

  const int n = t & 31, c0 = t >> 5;  // c0: 0..7
  float acc[16];
#pragma unroll
  for (int j = 0; j < 16; ++j) acc[j] = 0.f;
  for (int i = 0; i < 64; ++i) {
    float yv = ys[n][i];
#pragma unroll
    for (int j = 0; j < 16; ++j)
      acc[j] = fmaf(Ww[(c0 + 8 * j) * ICH + i], yv, acc[j]);
  }
#pragma unroll
  for (int j = 0; j < 16; ++j) {
    int c = c0 + 8 * j;
    size_t o = ((size_t)(b * CC + c) << 12) + n0 + n;
    out[o] = acc[j] + Wb[c] + x[o];
  }
}

extern "C" void kernel_launch(void* const* d_in, const int* in_sizes, int n_in,
                              void* d_out, int out_size, void* d_ws, size_t ws_size,
                              hipStream_t stream) {
  const float* x  = (const float*)d_in[0];
  const float* gw = (const float*)d_in[1];
  const float* gb = (const float*)d_in[2];
  const float* tw = (const float*)d_in[3];
  const float* tb = (const float*)d_in[4];
  const float* pw = (const float*)d_in[5];
  const float* pb = (const float*)d_in[6];
  const float* Ww = (const float*)d_in[7];
  const float* Wb = (const float*)d_in[8];
  float* out = (float*)d_out;

  char* ws = (char*)d_ws;
  u16*    th = (u16*)(ws);                        // 2MB
  u16*    ph = (u16*)(ws + (2ull << 20));         // 2MB
  u16*    gt = (u16*)(ws + (4ull << 20));         // 2MB
  u16*    yp = (u16*)(ws + (6ull << 20));         // SS*B*N*IC bf16 = 8MB
  float2* ml = (float2*)(ws + (14ull << 20));     // SS*B*N float2 = 512KB

  proj_kernel<<<512, 256, 0, stream>>>(x, gw, gb, tw, tb, pw, pb, th, ph, gt);
  attn_kernel<<<BB * 128 * SS, 128, 0, stream>>>(th, ph, gt, yp, ml);
  out_kernel<<<512, 256, 0, stream>>>(x, Ww, Wb, yp, ml, out);
}

// Round 3
// 86.600 us; speedup vs baseline: 2.5275x; 1.5414x over previous
//
#include <hip/hip_runtime.h>
#include <hip/hip_bf16.h>

#define BB  4
#define CC  128
#define ICH 64
#define NN  4096
#define SS  8            // KV split factor
#define KSPLIT (NN / SS) // 512 keys per block
#define MT (KSPLIT / 64) // 8 key-tiles per block

typedef __attribute__((ext_vector_type(4)))  float f32x4;
typedef __attribute__((ext_vector_type(16))) float f32x16;
typedef __attribute__((ext_vector_type(8)))  short bf16x8;
typedef unsigned short u16;

static __device__ __forceinline__ f32x16 mfma32(bf16x8 a, bf16x8 b, f32x16 c) {
  return __builtin_amdgcn_mfma_f32_32x32x16_bf16(a, b, c, 0, 0, 0);
}
static __device__ __forceinline__ u16 f2bf(float f) {
  __hip_bfloat16 h = __float2bfloat16(f);
  return *reinterpret_cast<u16*>(&h);
}
static __device__ __forceinline__ float bf2f(u16 u) {
  union { unsigned int i; float f; } v; v.i = ((unsigned int)u) << 16; return v.f;
}
static __device__ __forceinline__ void gl_lds16(const void* g, void* l) {
  __builtin_amdgcn_global_load_lds((const __attribute__((address_space(1))) void*)g,
                                   (__attribute__((address_space(3))) void*)l, 16, 0, 0);
}
static __device__ __forceinline__ f32x16 zero16() {
  f32x16 v;
#pragma unroll
  for (int i = 0; i < 16; ++i) v[i] = 0.f;
  return v;
}

// ---------------- Kernel 1: projections theta/phi -> [b][n][ic], g -> [b][ic][n] ----
// grid: BB * (NN/32) = 512 blocks, 256 threads
__global__ __launch_bounds__(256) void proj_kernel(
    const float* __restrict__ x,
    const float* __restrict__ gw, const float* __restrict__ gb,
    const float* __restrict__ tw, const float* __restrict__ tb,
    const float* __restrict__ pw, const float* __restrict__ pb,
    u16* __restrict__ th, u16* __restrict__ ph, u16* __restrict__ gt)
{
  __shared__ float xs[CC][32];
  __shared__ u16 gs[64][34];   // padded: conflict-free column writes
  const int b  = blockIdx.x >> 7;
  const int n0 = (blockIdx.x & 127) << 5;
  const int t  = threadIdx.x;

  for (int idx = t; idx < CC * 32; idx += 256) {
    int c = idx >> 5, n = idx & 31;
    xs[c][n] = x[((size_t)(b * CC + c) << 12) + n0 + n];
  }
  __syncthreads();

  const int ic = t & 63;
  const int nb = t >> 6;  // 0..3
  float ag[8], at[8], ap[8];
#pragma unroll
  for (int j = 0; j < 8; ++j) { ag[j] = 0.f; at[j] = 0.f; ap[j] = 0.f; }

  const float4* gw4 = (const float4*)(gw + ic * CC);
  const float4* tw4 = (const float4*)(tw + ic * CC);
  const float4* pw4 = (const float4*)(pw + ic * CC);
#pragma unroll 2
  for (int c4 = 0; c4 < CC / 4; ++c4) {
    float4 wg = gw4[c4], wt = tw4[c4], wp = pw4[c4];
#pragma unroll
    for (int cc = 0; cc < 4; ++cc) {
      float wgv = (&wg.x)[cc], wtv = (&wt.x)[cc], wpv = (&wp.x)[cc];
      int c = c4 * 4 + cc;
#pragma unroll
      for (int j = 0; j < 8; ++j) {
        float xv = xs[c][nb + 4 * j];
        ag[j] = fmaf(wgv, xv, ag[j]);
        at[j] = fmaf(wtv, xv, at[j]);
        ap[j] = fmaf(wpv, xv, ap[j]);
      }
    }
  }
  const float bgv = gb[ic], btv = tb[ic], bpv = pb[ic];
#pragma unroll
  for (int j = 0; j < 8; ++j) {
    int n = n0 + nb + 4 * j;
    size_t o = ((size_t)(b * NN + n)) * ICH + ic;
    th[o] = f2bf(at[j] + btv);
    ph[o] = f2bf(ap[j] + bpv);
    gs[ic][nb + 4 * j] = f2bf(ag[j] + bgv);
  }
  __syncthreads();
  {
    const int row = t >> 2, ch = t & 3;
    u16 tmp[8];
#pragma unroll
    for (int j = 0; j < 8; ++j) tmp[j] = gs[row][ch * 8 + j];
    size_t go = ((size_t)(b * ICH + row)) * NN + n0 + ch * 8;
    *(bf16x8*)(gt + go) = *(bf16x8*)tmp;
  }
}

// ---------------- Kernel 2: flash attention, 32x32 MFMA, no-max softmax -------------
// grid: BB * (NN/128) * SS = 1024 blocks, 256 threads (4 waves x 32 query rows)
__global__ __launch_bounds__(256) void attn_kernel(
    const u16* __restrict__ thp, const u16* __restrict__ php,
    const u16* __restrict__ gtp, u16* __restrict__ yp, float* __restrict__ Lq)
{
  __shared__ __align__(16) u16 ph_s[2][4096];  // [buf][64 keys][64 ic], 128B rows, swz
  __shared__ __align__(16) u16 gt_s[2][4096];  // [buf][64 ic][64 keys], 128B rows, swz
  __shared__ __align__(16) u16 p_s[4][1024];   // per-wave [32 q][32 k], 64B rows, swz

  const int t    = threadIdx.x;
  const int wave = t >> 6, lane = t & 63;
  const int l31  = lane & 31, hi = lane >> 5;
  const int bid  = blockIdx.x;
  const int s    = bid & 7;
  const int rb   = (bid >> 3) & 31;
  const int b    = bid >> 8;
  const int nw   = rb * 128 + wave * 32;
  const size_t bbase = (size_t)b * NN * ICH;

  const int swz  = (l31 & 7) << 4;   // for 128B-row tiles
  const int pswz = (l31 & 3) << 4;   // for 64B-row P tile
  const int koff = 16 * ((lane & 7) ^ (lane >> 3));

  // A-fragments of theta (held whole kernel): row nw+l31, k = ks*16 + hi*8
  bf16x8 aq[4];
#pragma unroll
  for (int ks = 0; ks < 4; ++ks)
    aq[ks] = *(const bf16x8*)(thp + bbase + (size_t)(nw + l31) * ICH + ks * 16 + hi * 8);

  f32x16 yacc[2];
  yacc[0] = zero16(); yacc[1] = zero16();
  float Lp[16];
#pragma unroll
  for (int r = 0; r < 16; ++r) Lp[r] = 0.f;

  const char* ph_g = (const char*)php + bbase * 2;
  const char* gt_g = (const char*)gtp + (size_t)b * ICH * NN * 2;
  const int m_start = s * KSPLIT;

  // stage tile mt into buffer buf
  auto stage = [&](int mt, int buf) {
    const int m0 = m_start + mt * 64;
#pragma unroll
    for (int u = 0; u < 2; ++u) {
      const int k = u * 4 + wave;
      const int row = k * 8 + (lane >> 3);
      gl_lds16(ph_g + (size_t)(m0 + row) * 128 + koff, (char*)ph_s[buf] + k * 1024);
      gl_lds16(gt_g + (size_t)row * (NN * 2) + m0 * 2 + koff, (char*)gt_s[buf] + k * 1024);
    }
  };

  stage(0, 0);
  for (int mt = 0; mt < MT; ++mt) {
    __syncthreads();                       // staged tile mt visible (vmcnt drained)
    if (mt + 1 < MT) stage(mt + 1, (mt + 1) & 1);
    const char* phb = (const char*)ph_s[mt & 1];
    const char* gtb = (const char*)gt_s[mt & 1];
    char* pw = (char*)p_s[wave];

#pragma unroll
    for (int c = 0; c < 2; ++c) {          // key chunks of 32
      // S chunk = theta . phi^T
      f32x16 sacc = zero16();
#pragma unroll
      for (int ks = 0; ks < 4; ++ks) {
        const int row = c * 32 + l31;
        bf16x8 bf = *(const bf16x8*)(phb + row * 128 + ((ks * 32 + hi * 16) ^ swz));
        sacc = mfma32(aq[ks], bf, sacc);
      }
      // no-max softmax: p = exp(s - 8); per-lane L partials
#pragma unroll
      for (int reg = 0; reg < 16; ++reg) {
        float p = __expf(sacc[reg] - 8.0f);
        Lp[reg] += p;
        const int q = (reg & 3) + 8 * (reg >> 2) + 4 * hi;
        *(u16*)(pw + q * 64 + ((l31 * 2) ^ ((q & 3) << 4))) = f2bf(p);
      }
      // PV for this chunk (keys c*32..c*32+31)
      bf16x8 pa[2];
#pragma unroll
      for (int k2 = 0; k2 < 2; ++k2)
        pa[k2] = *(const bf16x8*)(pw + l31 * 64 + ((k2 * 32 + hi * 16) ^ pswz));
#pragma unroll
      for (int ci = 0; ci < 2; ++ci) {
        const int icrow = ci * 32 + l31;
#pragma unroll
        for (int k2 = 0; k2 < 2; ++k2) {
          bf16x8 bg = *(const bf16x8*)(gtb + icrow * 128 +
                                       ((c * 64 + k2 * 32 + hi * 16) ^ swz));
          yacc[ci] = mfma32(pa[k2], bg, yacc[ci]);
        }
      }
    }
  }

  // reduce L partials across the 32 columns (lanes sharing hi)
#pragma unroll
  for (int reg = 0; reg < 16; ++reg) {
#pragma unroll
    for (int d = 1; d < 32; d <<= 1)
      Lp[reg] += __shfl_xor(Lp[reg], d);
  }

  const size_t pbase = ((size_t)s * BB + b) * NN;
#pragma unroll
  for (int ci = 0; ci < 2; ++ci) {
#pragma unroll
    for (int reg = 0; reg < 16; ++reg) {
      const int q = (reg & 3) + 8 * (reg >> 2) + 4 * hi;
      yp[(pbase + nw + q) * ICH + ci * 32 + l31] = f2bf(yacc[ci][reg]);
    }
  }
  if (l31 == 0) {
#pragma unroll
    for (int reg = 0; reg < 16; ++reg) {
      const int q = (reg & 3) + 8 * (reg >> 2) + 4 * hi;
      Lq[pbase + nw + q] = Lp[reg];
    }
  }
}

// ---------------- Kernel 3: combine partials, out = W.y + Wb + x (MFMA) -------------
// grid: BB * (NN/32) = 512 blocks, 256 threads (4 waves x 32 c-rows)
__global__ __launch_bounds__(256) void out_kernel(
    const float* __restrict__ x, const float* __restrict__ Ww,
    const float* __restrict__ Wb, const u16* __restrict__ yp,
    const float* __restrict__ Lq, float* __restrict__ out)
{
  __shared__ __align__(16) u16 ys[4096];   // [32 n][64 ic] bf16, 128B rows, swz
  const int t = threadIdx.x, lane = t & 63;
  const int wave = t >> 6, l31 = lane & 31, hi = lane >> 5;
  const int b  = blockIdx.x >> 7;
  const int n0 = (blockIdx.x & 127) << 5;

  // phase 0: combine the SS partials -> normalized y (bf16) in LDS
  {
    const int n = t >> 3, i8 = t & 7;
    float den = 0.f;
#pragma unroll
    for (int s = 0; s < SS; ++s) den += Lq[((size_t)s * BB + b) * NN + n0 + n];
    float num[8];
#pragma unroll
    for (int j = 0; j < 8; ++j) num[j] = 0.f;
#pragma unroll
    for (int s = 0; s < SS; ++s) {
      bf16x8 v = *(const bf16x8*)(yp + (((size_t)s * BB + b) * NN + n0 + n) * ICH + i8 * 8);
#pragma unroll
      for (int j = 0; j < 8; ++j) num[j] += bf2f((u16)v[j]);
    }
    float rd = 1.f / den;
    u16 o[8];
#pragma unroll
    for (int j = 0; j < 8; ++j) o[j] = f2bf(num[j] * rd);
    *(bf16x8*)((char*)ys + n * 128 + ((i8 * 16) ^ ((n & 7) << 4))) = *(bf16x8*)o;
  }
  __syncthreads();

  // phase 1: W.y via MFMA; wave handles c-chunk wave*32
  f32x16 acc = zero16();
  const int crow = wave * 32 + l31;
#pragma unroll
  for (int ks = 0; ks < 4; ++ks) {
    const float* wp = Ww + crow * ICH + ks * 16 + hi * 8;
    float4 w0 = *(const float4*)wp, w1 = *(const float4*)(wp + 4);
    u16 af[8];
    af[0] = f2bf(w0.x); af[1] = f2bf(w0.y); af[2] = f2bf(w0.z); af[3] = f2bf(w0.w);
    af[4] = f2bf(w1.x); af[5] = f2bf(w1.y); af[6] = f2bf(w1.z); af[7] = f2bf(w1.w);
    bf16x8 bf = *(const bf16x8*)((char*)ys + l31 * 128 +
                                 ((ks * 32 + hi * 16) ^ ((l31 & 7) << 4)));
    acc = mfma32(*(const bf16x8*)af, bf, acc);
  }
#pragma unroll
  for (int reg = 0; reg < 16; ++reg) {
    const int c = wave * 32 + (reg & 3) + 8 * (reg >> 2) + 4 * hi;
    size_t o = ((size_t)(b * CC + c) << 12) + n0 + l31;
    out[o] = acc[reg] + Wb[c] + x[o];
  }
}

extern "C" void kernel_launch(void* const* d_in, const int* in_sizes, int n_in,
                              void* d_out, int out_size, void* d_ws, size_t ws_size,
                              hipStream_t stream) {
  const float* x  = (const float*)d_in[0];
  const float* gw = (const float*)d_in[1];
  const float* gb = (const float*)d_in[2];
  const float* tw = (const float*)d_in[3];
  const float* tb = (const float*)d_in[4];
  const float* pw = (const float*)d_in[5];
  const float* pb = (const float*)d_in[6];
  const float* Ww = (const float*)d_in[7];
  const float* Wb = (const float*)d_in[8];
  float* out = (float*)d_out;

  char* ws = (char*)d_ws;
  u16*   th = (u16*)(ws);                      // 2MB
  u16*   ph = (u16*)(ws + (2ull << 20));       // 2MB
  u16*   gt = (u16*)(ws + (4ull << 20));       // 2MB
  u16*   yp = (u16*)(ws + (6ull << 20));       // SS*B*N*IC bf16 = 16MB
  float* Lq = (float*)(ws + (22ull << 20));    // SS*B*N f32 = 512KB

  proj_kernel<<<512, 256, 0, stream>>>(x, gw, gb, tw, tb, pw, pb, th, ph, gt);
  attn_kernel<<<BB * (NN / 128) * SS, 256, 0, stream>>>(th, ph, gt, yp, Lq);
  out_kernel<<<512, 256, 0, stream>>>(x, Ww, Wb, yp, Lq, out);
}